// Round 1
// baseline (4080.788 us; speedup 1.0000x reference)
//
#include <hip/hip_runtime.h>
#include <hip/hip_bf16.h>

// Problem constants (from reference): IN=512, OUT=512, H=8, B=4, FH=64
#define KDIM 512
#define ODIM 512
#define NB 4
#define NH 8
#define FH 64
#define BFH 256   // B*FH
#define HB 32     // H*B
#define LN_EPS 1e-5f

// ---------------------------------------------------------------------------
// degree via atomics over dst
__global__ void deg_kernel(const int* __restrict__ dst, float* __restrict__ deg, int E) {
    int i = blockIdx.x * blockDim.x + threadIdx.x;
    if (i < E) atomicAdd(&deg[dst[i]], 1.0f);
}

// dinv[v] = rsqrt(deg[v] + 1)   (self-loop adds 1; deg >= 1 so where() is moot)
__global__ void dinv_kernel(float* __restrict__ deg, int N) {
    int i = blockIdx.x * blockDim.x + threadIdx.x;
    if (i < N) deg[i] = rsqrtf(deg[i] + 1.0f);
}

// ---------------------------------------------------------------------------
// Tiled fp32 GEMM: C[M,Ncols] = A[M,K] @ B[K,Ncols] (+ bias)
// 64x64 tile, 256 threads, 4x4 per thread, TK=16
#define TILE 64
#define TK 16
__global__ __launch_bounds__(256) void gemm_kernel(
        const float* __restrict__ A, const float* __restrict__ Bm,
        const float* __restrict__ bias, float* __restrict__ C,
        int M, int K, int Ncols) {
    __shared__ float As[TK][TILE + 1];
    __shared__ float Bs[TK][TILE + 1];
    int t = threadIdx.x;
    int tx = t & 15, ty = t >> 4;
    int row0 = blockIdx.y * TILE;
    int col0 = blockIdx.x * TILE;
    float acc[4][4] = {};
    for (int k0 = 0; k0 < K; k0 += TK) {
        // A tile: 64 rows x 16 k  -> As[k][m]
        #pragma unroll
        for (int i = 0; i < 4; i++) {
            int idx = t + i * 256;           // 0..1023
            int m = idx >> 4, kk = idx & 15;
            int gr = row0 + m;
            As[kk][m] = (gr < M) ? A[(long)gr * K + k0 + kk] : 0.0f;
        }
        // B tile: 16 k x 64 cols -> Bs[k][n]
        #pragma unroll
        for (int i = 0; i < 4; i++) {
            int idx = t + i * 256;
            int kk = idx >> 6, nn = idx & 63;
            int gc = col0 + nn;
            Bs[kk][nn] = (gc < Ncols) ? Bm[(long)(k0 + kk) * Ncols + gc] : 0.0f;
        }
        __syncthreads();
        #pragma unroll
        for (int kk = 0; kk < TK; kk++) {
            float a[4], b[4];
            #pragma unroll
            for (int i = 0; i < 4; i++) a[i] = As[kk][ty * 4 + i];
            #pragma unroll
            for (int j = 0; j < 4; j++) b[j] = Bs[kk][tx * 4 + j];
            #pragma unroll
            for (int i = 0; i < 4; i++)
                #pragma unroll
                for (int j = 0; j < 4; j++)
                    acc[i][j] += a[i] * b[j];
        }
        __syncthreads();
    }
    #pragma unroll
    for (int i = 0; i < 4; i++) {
        int gr = row0 + ty * 4 + i;
        if (gr >= M) continue;
        #pragma unroll
        for (int j = 0; j < 4; j++) {
            int gc = col0 + tx * 4 + j;
            if (gc < Ncols)
                C[(long)gr * Ncols + gc] = acc[i][j] + (bias ? bias[gc] : 0.0f);
        }
    }
}

// ---------------------------------------------------------------------------
// Edge scatter: one wave (64 lanes) per edge; each lane handles 4 floats.
// agg[dst] += bases[src] * dinv[src]*dinv[dst]
__global__ __launch_bounds__(256) void scatter_kernel(
        const int* __restrict__ src, const int* __restrict__ dst,
        const float* __restrict__ dinv, const float* __restrict__ bases,
        float* __restrict__ agg, int E) {
    long wave = ((long)blockIdx.x * blockDim.x + threadIdx.x) >> 6;
    int lane = threadIdx.x & 63;
    if (wave >= E) return;
    int s = src[wave], d = dst[wave];
    float nrm = dinv[s] * dinv[d];
    float4 v = ((const float4*)(bases + (long)s * BFH))[lane];
    float* ap = agg + (long)d * BFH + lane * 4;
    atomicAdd(ap + 0, v.x * nrm);
    atomicAdd(ap + 1, v.y * nrm);
    atomicAdd(ap + 2, v.z * nrm);
    atomicAdd(ap + 3, v.w * nrm);
}

// ---------------------------------------------------------------------------
// Per-node combine + residual + LayerNorm + ReLU. One block (512 thr) per node.
// out already holds the residual (x @ W_res + b_res) from the res GEMM.
__global__ __launch_bounds__(512) void combine_kernel(
        const float* __restrict__ agg, const float* __restrict__ bases,
        const float* __restrict__ weight, const float* __restrict__ dinv,
        const float* __restrict__ conv_bias, const float* __restrict__ gamma,
        const float* __restrict__ beta, float* __restrict__ out) {
    int n = blockIdx.x;
    int t = threadIdx.x;            // 0..511
    __shared__ float w[HB];
    __shared__ float rs[8], rs2[8];
    __shared__ float mv[2];
    if (t < HB) w[t] = weight[(long)n * HB + t];
    __syncthreads();

    int h = t >> 6, f = t & 63;
    float di = dinv[n];
    float self = di * di;
    float conv = 0.0f;
    #pragma unroll
    for (int b = 0; b < NB; b++) {
        long idx = (long)n * BFH + b * FH + f;
        float a = agg[idx] + bases[idx] * self;
        conv += w[h * NB + b] * a;
    }
    float val = conv + conv_bias[t] + out[(long)n * ODIM + t];

    // block reduction: sum and sum of squares over 512 values
    float s = val, s2 = val * val;
    #pragma unroll
    for (int o = 32; o > 0; o >>= 1) {
        s  += __shfl_down(s, o, 64);
        s2 += __shfl_down(s2, o, 64);
    }
    int wid = t >> 6, lane = t & 63;
    if (lane == 0) { rs[wid] = s; rs2[wid] = s2; }
    __syncthreads();
    if (t == 0) {
        float S = 0.f, S2 = 0.f;
        #pragma unroll
        for (int i = 0; i < 8; i++) { S += rs[i]; S2 += rs2[i]; }
        float mu = S / (float)ODIM;
        float var = S2 / (float)ODIM - mu * mu;
        mv[0] = mu;
        mv[1] = rsqrtf(var + LN_EPS);
    }
    __syncthreads();
    float o = (val - mv[0]) * mv[1] * gamma[t] + beta[t];
    out[(long)n * ODIM + t] = fmaxf(o, 0.0f);
}

// ---------------------------------------------------------------------------
extern "C" void kernel_launch(void* const* d_in, const int* in_sizes, int n_in,
                              void* d_out, int out_size, void* d_ws, size_t ws_size,
                              hipStream_t stream) {
    const float* x         = (const float*)d_in[0];
    const int*   ei        = (const int*)d_in[1];
    const float* W_bases   = (const float*)d_in[2];
    const float* W_comb    = (const float*)d_in[3];
    const float* b_comb    = (const float*)d_in[4];
    const float* conv_bias = (const float*)d_in[5];
    const float* W_res     = (const float*)d_in[6];
    const float* b_res     = (const float*)d_in[7];
    const float* gamma     = (const float*)d_in[8];
    const float* beta      = (const float*)d_in[9];

    int N = in_sizes[0] / KDIM;
    int E = in_sizes[1] / 2;
    const int* src = ei;
    const int* dst = ei + E;

    float* ws = (float*)d_ws;
    float* deg    = ws;                          // N  (becomes dinv in place)
    float* agg    = ws + N;                      // N*256
    float* bases  = agg + (long)N * BFH;         // N*256
    float* weight = bases + (long)N * BFH;       // N*32
    float* out    = (float*)d_out;               // res GEMM target, then final

    // zero deg + agg (contiguous region of N*(1+256) floats); ws is 0xAA-poisoned
    hipMemsetAsync(deg, 0, sizeof(float) * (size_t)N * (1 + BFH), stream);

    deg_kernel<<<(E + 255) / 256, 256, 0, stream>>>(dst, deg, E);
    dinv_kernel<<<(N + 255) / 256, 256, 0, stream>>>(deg, N);

    dim3 gb((BFH + TILE - 1) / TILE, (N + TILE - 1) / TILE);
    gemm_kernel<<<gb, 256, 0, stream>>>(x, W_bases, nullptr, bases, N, KDIM, BFH);
    dim3 gc((HB + TILE - 1) / TILE, (N + TILE - 1) / TILE);
    gemm_kernel<<<gc, 256, 0, stream>>>(x, W_comb, b_comb, weight, N, KDIM, HB);
    dim3 gr((ODIM + TILE - 1) / TILE, (N + TILE - 1) / TILE);
    gemm_kernel<<<gr, 256, 0, stream>>>(x, W_res, b_res, out, N, KDIM, ODIM);

    long nblk = ((long)E + 3) / 4;   // 4 waves/block, 1 edge per wave
    scatter_kernel<<<nblk, 256, 0, stream>>>(src, dst, deg, bases, agg, E);

    combine_kernel<<<N, 512, 0, stream>>>(agg, bases, weight, deg,
                                          conv_bias, gamma, beta, out);
}

// Round 2
// 1586.819 us; speedup vs baseline: 2.5717x; 2.5717x over previous
//
#include <hip/hip_runtime.h>
#include <hip/hip_bf16.h>

// Problem constants (from reference): IN=512, OUT=512, H=8, B=4, FH=64
#define KDIM 512
#define ODIM 512
#define NB 4
#define NH 8
#define FH 64
#define BFH 256   // B*FH
#define HB 32     // H*B
#define LN_EPS 1e-5f

#define SCAN_T 1024

// ---------------------------------------------------------------------------
// integer degree count over dst
__global__ void deg_kernel(const int* __restrict__ dst, int* __restrict__ deg, int E) {
    int i = blockIdx.x * blockDim.x + threadIdx.x;
    if (i < E) atomicAdd(&deg[dst[i]], 1);
}

// dinv[v] = rsqrt(deg[v] + 1)   (self-loop adds 1)
__global__ void dinv_kernel(const int* __restrict__ deg, float* __restrict__ dinv, int N) {
    int i = blockIdx.x * blockDim.x + threadIdx.x;
    if (i < N) dinv[i] = rsqrtf((float)deg[i] + 1.0f);
}

// single-block exclusive scan of deg[0..N) -> offsets[0..N], plus working copy woff
__global__ __launch_bounds__(SCAN_T) void scan_kernel(
        const int* __restrict__ deg, int* __restrict__ offsets,
        int* __restrict__ woff, int N) {
    __shared__ int sm[SCAN_T];
    int t = threadIdx.x;
    int C = (N + SCAN_T - 1) / SCAN_T;
    int start = t * C;
    int end = min(start + C, N);
    int local = 0;
    for (int i = start; i < end; i++) local += deg[i];
    sm[t] = local;
    __syncthreads();
    // Hillis-Steele inclusive scan
    for (int o = 1; o < SCAN_T; o <<= 1) {
        int v = (t >= o) ? sm[t - o] : 0;
        __syncthreads();
        sm[t] += v;
        __syncthreads();
    }
    int running = sm[t] - local;   // exclusive base
    for (int i = start; i < end; i++) {
        offsets[i] = running;
        woff[i] = running;
        running += deg[i];
    }
    if (end == N && start < N) offsets[N] = running;   // == E
}

// bin edges by dst: ebuf[offsets[d] + ticket] = src
__global__ void fill_kernel(const int* __restrict__ src, const int* __restrict__ dst,
                            int* __restrict__ woff, int* __restrict__ ebuf, int E) {
    int i = blockIdx.x * blockDim.x + threadIdx.x;
    if (i < E) {
        int pos = atomicAdd(&woff[dst[i]], 1);
        ebuf[pos] = src[i];
    }
}

// ---------------------------------------------------------------------------
// Gather: one wave per dst node. Lane holds float4 (cols lane*4..lane*4+3).
// agg[n] = bases[n]*dinv[n]^2 + sum_{e in CSR[n]} bases[src_e]*dinv[src_e]*dinv[n]
__global__ __launch_bounds__(256) void gather_kernel(
        const int* __restrict__ offsets, const int* __restrict__ ebuf,
        const float* __restrict__ dinv, const float* __restrict__ bases,
        float* __restrict__ agg, int N) {
    int wave = (blockIdx.x * blockDim.x + threadIdx.x) >> 6;
    int lane = threadIdx.x & 63;
    if (wave >= N) return;
    int n = wave;
    float di = dinv[n];
    float self = di * di;
    float4 v = ((const float4*)(bases + (long)n * BFH))[lane];
    float ax = v.x * self, ay = v.y * self, az = v.z * self, aw = v.w * self;
    int e = offsets[n], end = offsets[n + 1];
    for (; e + 1 < end; e += 2) {
        int s0 = ebuf[e], s1 = ebuf[e + 1];
        float n0 = dinv[s0] * di, n1 = dinv[s1] * di;
        float4 v0 = ((const float4*)(bases + (long)s0 * BFH))[lane];
        float4 v1 = ((const float4*)(bases + (long)s1 * BFH))[lane];
        ax += v0.x * n0 + v1.x * n1;
        ay += v0.y * n0 + v1.y * n1;
        az += v0.z * n0 + v1.z * n1;
        aw += v0.w * n0 + v1.w * n1;
    }
    if (e < end) {
        int s0 = ebuf[e];
        float n0 = dinv[s0] * di;
        float4 v0 = ((const float4*)(bases + (long)s0 * BFH))[lane];
        ax += v0.x * n0; ay += v0.y * n0; az += v0.z * n0; aw += v0.w * n0;
    }
    float4 r; r.x = ax; r.y = ay; r.z = az; r.w = aw;
    ((float4*)(agg + (long)n * BFH))[lane] = r;
}

// ---------------------------------------------------------------------------
// Tiled fp32 GEMM: C[M,Ncols] = A[M,K] @ B[K,Ncols] (+ bias)
#define TILE 64
#define TK 16
__global__ __launch_bounds__(256) void gemm_kernel(
        const float* __restrict__ A, const float* __restrict__ Bm,
        const float* __restrict__ bias, float* __restrict__ C,
        int M, int K, int Ncols) {
    __shared__ float As[TK][TILE + 1];
    __shared__ float Bs[TK][TILE + 1];
    int t = threadIdx.x;
    int tx = t & 15, ty = t >> 4;
    int row0 = blockIdx.y * TILE;
    int col0 = blockIdx.x * TILE;
    float acc[4][4] = {};
    for (int k0 = 0; k0 < K; k0 += TK) {
        #pragma unroll
        for (int i = 0; i < 4; i++) {
            int idx = t + i * 256;
            int m = idx >> 4, kk = idx & 15;
            int gr = row0 + m;
            As[kk][m] = (gr < M) ? A[(long)gr * K + k0 + kk] : 0.0f;
        }
        #pragma unroll
        for (int i = 0; i < 4; i++) {
            int idx = t + i * 256;
            int kk = idx >> 6, nn = idx & 63;
            int gc = col0 + nn;
            Bs[kk][nn] = (gc < Ncols) ? Bm[(long)(k0 + kk) * Ncols + gc] : 0.0f;
        }
        __syncthreads();
        #pragma unroll
        for (int kk = 0; kk < TK; kk++) {
            float a[4], b[4];
            #pragma unroll
            for (int i = 0; i < 4; i++) a[i] = As[kk][ty * 4 + i];
            #pragma unroll
            for (int j = 0; j < 4; j++) b[j] = Bs[kk][tx * 4 + j];
            #pragma unroll
            for (int i = 0; i < 4; i++)
                #pragma unroll
                for (int j = 0; j < 4; j++)
                    acc[i][j] += a[i] * b[j];
        }
        __syncthreads();
    }
    #pragma unroll
    for (int i = 0; i < 4; i++) {
        int gr = row0 + ty * 4 + i;
        if (gr >= M) continue;
        #pragma unroll
        for (int j = 0; j < 4; j++) {
            int gc = col0 + tx * 4 + j;
            if (gc < Ncols)
                C[(long)gr * Ncols + gc] = acc[i][j] + (bias ? bias[gc] : 0.0f);
        }
    }
}

// ---------------------------------------------------------------------------
// Per-node combine + residual + LayerNorm + ReLU. One block (512 thr) per node.
// out already holds the residual (x @ W_res + b_res); agg includes self-loop.
__global__ __launch_bounds__(512) void combine_kernel(
        const float* __restrict__ agg, const float* __restrict__ weight,
        const float* __restrict__ conv_bias, const float* __restrict__ gamma,
        const float* __restrict__ beta, float* __restrict__ out) {
    int n = blockIdx.x;
    int t = threadIdx.x;            // 0..511
    __shared__ float w[HB];
    __shared__ float rs[8], rs2[8];
    __shared__ float mv[2];
    if (t < HB) w[t] = weight[(long)n * HB + t];
    __syncthreads();

    int h = t >> 6, f = t & 63;
    float conv = 0.0f;
    #pragma unroll
    for (int b = 0; b < NB; b++) {
        float a = agg[(long)n * BFH + b * FH + f];
        conv += w[h * NB + b] * a;
    }
    float val = conv + conv_bias[t] + out[(long)n * ODIM + t];

    float s = val, s2 = val * val;
    #pragma unroll
    for (int o = 32; o > 0; o >>= 1) {
        s  += __shfl_down(s, o, 64);
        s2 += __shfl_down(s2, o, 64);
    }
    int wid = t >> 6, lane = t & 63;
    if (lane == 0) { rs[wid] = s; rs2[wid] = s2; }
    __syncthreads();
    if (t == 0) {
        float S = 0.f, S2 = 0.f;
        #pragma unroll
        for (int i = 0; i < 8; i++) { S += rs[i]; S2 += rs2[i]; }
        float mu = S / (float)ODIM;
        float var = S2 / (float)ODIM - mu * mu;
        mv[0] = mu;
        mv[1] = rsqrtf(var + LN_EPS);
    }
    __syncthreads();
    float o = (val - mv[0]) * mv[1] * gamma[t] + beta[t];
    out[(long)n * ODIM + t] = fmaxf(o, 0.0f);
}

// ---------------------------------------------------------------------------
extern "C" void kernel_launch(void* const* d_in, const int* in_sizes, int n_in,
                              void* d_out, int out_size, void* d_ws, size_t ws_size,
                              hipStream_t stream) {
    const float* x         = (const float*)d_in[0];
    const int*   ei        = (const int*)d_in[1];
    const float* W_bases   = (const float*)d_in[2];
    const float* W_comb    = (const float*)d_in[3];
    const float* b_comb    = (const float*)d_in[4];
    const float* conv_bias = (const float*)d_in[5];
    const float* W_res     = (const float*)d_in[6];
    const float* b_res     = (const float*)d_in[7];
    const float* gamma     = (const float*)d_in[8];
    const float* beta      = (const float*)d_in[9];

    int N = in_sizes[0] / KDIM;
    int E = in_sizes[1] / 2;
    const int* src = ei;
    const int* dst = ei + E;

    char* ws = (char*)d_ws;
    int*   deg     = (int*)ws;                       ws += sizeof(int) * (size_t)N;
    int*   offsets = (int*)ws;                       ws += sizeof(int) * (size_t)(N + 1);
    int*   woff    = (int*)ws;                       ws += sizeof(int) * (size_t)N;
    int*   ebuf    = (int*)ws;                       ws += sizeof(int) * (size_t)E;
    float* dinv    = (float*)ws;                     ws += sizeof(float) * (size_t)N;
    float* agg     = (float*)ws;                     ws += sizeof(float) * (size_t)N * BFH;
    float* bases   = (float*)ws;                     ws += sizeof(float) * (size_t)N * BFH;
    float* weight  = (float*)ws;                     ws += sizeof(float) * (size_t)N * HB;
    float* out     = (float*)d_out;

    // only deg needs zeroing; everything else is fully written before read
    hipMemsetAsync(deg, 0, sizeof(int) * (size_t)N, stream);

    deg_kernel<<<(E + 255) / 256, 256, 0, stream>>>(dst, deg, E);
    dinv_kernel<<<(N + 255) / 256, 256, 0, stream>>>(deg, dinv, N);
    scan_kernel<<<1, SCAN_T, 0, stream>>>(deg, offsets, woff, N);
    fill_kernel<<<(E + 255) / 256, 256, 0, stream>>>(src, dst, woff, ebuf, E);

    dim3 gb((BFH + TILE - 1) / TILE, (N + TILE - 1) / TILE);
    gemm_kernel<<<gb, 256, 0, stream>>>(x, W_bases, nullptr, bases, N, KDIM, BFH);
    dim3 gc((HB + TILE - 1) / TILE, (N + TILE - 1) / TILE);
    gemm_kernel<<<gc, 256, 0, stream>>>(x, W_comb, b_comb, weight, N, KDIM, HB);
    dim3 gr((ODIM + TILE - 1) / TILE, (N + TILE - 1) / TILE);
    gemm_kernel<<<gr, 256, 0, stream>>>(x, W_res, b_res, out, N, KDIM, ODIM);

    gather_kernel<<<(N + 3) / 4, 256, 0, stream>>>(offsets, ebuf, dinv, bases, agg, N);

    combine_kernel<<<N, 512, 0, stream>>>(agg, weight, conv_bias, gamma, beta, out);
}

// Round 3
// 643.962 us; speedup vs baseline: 6.3370x; 2.4642x over previous
//
#include <hip/hip_runtime.h>
#include <hip/hip_bf16.h>

// Problem constants: IN=512, OUT=512, H=8, B=4, FH=64
#define KDIM 512
#define ODIM 512
#define NB 4
#define NH 8
#define FH 64
#define BFH 256   // B*FH
#define HB 32     // H*B
#define NCAT 896  // 256 bases + 32 comb + 512 res + 96 pad
#define LN_EPS 1e-5f

#define SCAN_T 1024

typedef __attribute__((ext_vector_type(8))) short short8;
typedef __attribute__((ext_vector_type(4))) float floatx4;

__device__ __forceinline__ float b2f(unsigned short u) {
    union { unsigned int i; float f; } v; v.i = ((unsigned int)u) << 16; return v.f;
}

// ---------------------------------------------------------------------------
__global__ void deg_kernel(const int* __restrict__ dst, int* __restrict__ deg, int E) {
    int i = blockIdx.x * blockDim.x + threadIdx.x;
    if (i < E) atomicAdd(&deg[dst[i]], 1);
}

__global__ void dinv_kernel(const int* __restrict__ deg, float* __restrict__ dinv, int N) {
    int i = blockIdx.x * blockDim.x + threadIdx.x;
    if (i < N) dinv[i] = rsqrtf((float)deg[i] + 1.0f);
}

// single-block exclusive scan of deg -> offsets[0..N], working copy woff
__global__ __launch_bounds__(SCAN_T) void scan_kernel(
        const int* __restrict__ deg, int* __restrict__ offsets,
        int* __restrict__ woff, int N) {
    __shared__ int sm[SCAN_T];
    int t = threadIdx.x;
    int C = (N + SCAN_T - 1) / SCAN_T;
    int start = t * C;
    int end = min(start + C, N);
    int local = 0;
    for (int i = start; i < end; i++) local += deg[i];
    sm[t] = local;
    __syncthreads();
    for (int o = 1; o < SCAN_T; o <<= 1) {
        int v = (t >= o) ? sm[t - o] : 0;
        __syncthreads();
        sm[t] += v;
        __syncthreads();
    }
    int running = sm[t] - local;
    for (int i = start; i < end; i++) {
        offsets[i] = running;
        woff[i] = running;
        running += deg[i];
    }
    if (end == N && start < N) offsets[N] = running;
}

__global__ void fill_kernel(const int* __restrict__ src, const int* __restrict__ dst,
                            int* __restrict__ woff, int* __restrict__ ebuf, int E) {
    int i = blockIdx.x * blockDim.x + threadIdx.x;
    if (i < E) {
        int pos = atomicAdd(&woff[dst[i]], 1);
        ebuf[pos] = src[i];
    }
}

// ---------------------------------------------------------------------------
// x fp32 -> bf16
__global__ __launch_bounds__(256) void cvt_x_kernel(
        const float* __restrict__ x, unsigned short* __restrict__ xb, long total4) {
    long i = (long)blockIdx.x * blockDim.x + threadIdx.x;
    if (i >= total4) return;
    float4 v = ((const float4*)x)[i];
    ushort4 u;
    __hip_bfloat16 h;
    h = __float2bfloat16(v.x); u.x = *(unsigned short*)&h;
    h = __float2bfloat16(v.y); u.y = *(unsigned short*)&h;
    h = __float2bfloat16(v.z); u.z = *(unsigned short*)&h;
    h = __float2bfloat16(v.w); u.w = *(unsigned short*)&h;
    ((ushort4*)xb)[i] = u;
}

// Stage WcatT [NCAT=896 cols][512 k] bf16 (transposed concat of the 3 weights)
// and bias_cat[896].
__global__ __launch_bounds__(256) void stage_w_kernel(
        const float* __restrict__ Wb, const float* __restrict__ Wc,
        const float* __restrict__ Wr, const float* __restrict__ bcomb,
        const float* __restrict__ bres,
        unsigned short* __restrict__ wT, float* __restrict__ bias_cat) {
    int idx = blockIdx.x * blockDim.x + threadIdx.x;
    if (idx >= NCAT * KDIM) return;
    int c = idx >> 9, k = idx & (KDIM - 1);
    float v;
    if (c < BFH)            v = Wb[(size_t)k * BFH + c];
    else if (c < BFH + HB)  v = Wc[(size_t)k * HB + (c - BFH)];
    else if (c < BFH + HB + ODIM) v = Wr[(size_t)k * ODIM + (c - BFH - HB)];
    else                    v = 0.0f;
    __hip_bfloat16 h = __float2bfloat16(v);
    wT[(size_t)c * KDIM + k] = *(unsigned short*)&h;
    if (k == 0) {
        float bv = 0.0f;
        if (c >= BFH && c < BFH + HB) bv = bcomb[c - BFH];
        else if (c >= BFH + HB && c < BFH + HB + ODIM) bv = bres[c - BFH - HB];
        bias_cat[c] = bv;
    }
}

// ---------------------------------------------------------------------------
// Fused bf16 MFMA GEMM: C[N, 896] = xb[N,512] @ WcatT^T, epilogue routes
// cols [0,256)->bases(bf16), [256,288)->weight(f32), [288,800)->outr(f32).
#define BM 128
#define BN 128
#define BK 32
#define LDK 40   // padded LDS k-stride (elements); 80B rows keep 16B alignment

__global__ __launch_bounds__(256) void mfma_gemm_kernel(
        const unsigned short* __restrict__ xb,   // [N,512] bf16 bits
        const unsigned short* __restrict__ wT,   // [896,512] bf16 bits
        const float* __restrict__ bias_cat,      // [896]
        unsigned short* __restrict__ bases,      // [N,256] bf16 bits
        float* __restrict__ weight,              // [N,32]
        float* __restrict__ outr,                // [N,512]
        int N) {
    __shared__ short As[BM * LDK];
    __shared__ short Bs[BN * LDK];
    int t = threadIdx.x;
    int lane = t & 63, wave = t >> 6;
    int wr = wave >> 1, wc = wave & 1;
    int quad = lane >> 4, m = lane & 15;
    int row0 = blockIdx.y * BM;
    int col0 = blockIdx.x * BN;

    floatx4 zero4 = {0.f, 0.f, 0.f, 0.f};
    floatx4 acc[4][4];
    #pragma unroll
    for (int i = 0; i < 4; i++)
        #pragma unroll
        for (int j = 0; j < 4; j++) acc[i][j] = zero4;

    // staging map: chunk c (0..511): row=c>>2, k-offset=(c&3)*8; thread does c=t, t+256
    int ar1 = t >> 2,        ak1 = (t & 3) * 8;
    int ar2 = (t + 256) >> 2, ak2 = ((t + 256) & 3) * 8;
    size_t aG1 = (size_t)min(row0 + ar1, N - 1) * KDIM + ak1;
    size_t aG2 = (size_t)min(row0 + ar2, N - 1) * KDIM + ak2;
    size_t bG1 = (size_t)(col0 + ar1) * KDIM + ak1;
    size_t bG2 = (size_t)(col0 + ar2) * KDIM + ak2;

    for (int k0 = 0; k0 < KDIM; k0 += BK) {
        int4 av1 = *(const int4*)(xb + aG1 + k0);
        int4 av2 = *(const int4*)(xb + aG2 + k0);
        int4 bv1 = *(const int4*)(wT + bG1 + k0);
        int4 bv2 = *(const int4*)(wT + bG2 + k0);
        __syncthreads();
        *(int4*)(&As[ar1 * LDK + ak1]) = av1;
        *(int4*)(&As[ar2 * LDK + ak2]) = av2;
        *(int4*)(&Bs[ar1 * LDK + ak1]) = bv1;
        *(int4*)(&Bs[ar2 * LDK + ak2]) = bv2;
        __syncthreads();

        short8 a[4], b[4];
        #pragma unroll
        for (int i = 0; i < 4; i++)
            a[i] = *(const short8*)(&As[(wr * 64 + i * 16 + m) * LDK + quad * 8]);
        #pragma unroll
        for (int j = 0; j < 4; j++)
            b[j] = *(const short8*)(&Bs[(wc * 64 + j * 16 + m) * LDK + quad * 8]);
        #pragma unroll
        for (int i = 0; i < 4; i++)
            #pragma unroll
            for (int j = 0; j < 4; j++)
                acc[i][j] = __builtin_amdgcn_mfma_f32_16x16x32_bf16(
                    a[i], b[j], acc[i][j], 0, 0, 0);
    }

    // epilogue: C/D layout col=lane&15, row=quad*4+reg
    float bj[4];
    #pragma unroll
    for (int j = 0; j < 4; j++) bj[j] = bias_cat[col0 + wc * 64 + j * 16 + m];

    #pragma unroll
    for (int i = 0; i < 4; i++) {
        #pragma unroll
        for (int r = 0; r < 4; r++) {
            int gr = row0 + wr * 64 + i * 16 + quad * 4 + r;
            if (gr >= N) continue;
            #pragma unroll
            for (int j = 0; j < 4; j++) {
                int gc = col0 + wc * 64 + j * 16 + m;
                float v = acc[i][j][r] + bj[j];
                if (gc < BFH) {
                    __hip_bfloat16 h = __float2bfloat16(v);
                    bases[(size_t)gr * BFH + gc] = *(unsigned short*)&h;
                } else if (gc < BFH + HB) {
                    weight[(size_t)gr * HB + (gc - BFH)] = v;
                } else if (gc < BFH + HB + ODIM) {
                    outr[(size_t)gr * ODIM + (gc - BFH - HB)] = v;
                }
            }
        }
    }
}

// ---------------------------------------------------------------------------
// Gather: one wave per dst node; lane holds 4 bf16 cols.
__global__ __launch_bounds__(256) void gather_kernel(
        const int* __restrict__ offsets, const int* __restrict__ ebuf,
        const float* __restrict__ dinv, const unsigned short* __restrict__ bases,
        float* __restrict__ agg, int N) {
    int wave = (blockIdx.x * blockDim.x + threadIdx.x) >> 6;
    int lane = threadIdx.x & 63;
    if (wave >= N) return;
    int n = wave;
    float di = dinv[n];
    float self = di * di;
    ushort4 u = ((const ushort4*)(bases + (size_t)n * BFH))[lane];
    float ax = b2f(u.x) * self, ay = b2f(u.y) * self;
    float az = b2f(u.z) * self, aw = b2f(u.w) * self;
    int e = offsets[n], end = offsets[n + 1];
    for (; e + 1 < end; e += 2) {
        int s0 = ebuf[e], s1 = ebuf[e + 1];
        float n0 = dinv[s0] * di, n1 = dinv[s1] * di;
        ushort4 u0 = ((const ushort4*)(bases + (size_t)s0 * BFH))[lane];
        ushort4 u1 = ((const ushort4*)(bases + (size_t)s1 * BFH))[lane];
        ax += b2f(u0.x) * n0 + b2f(u1.x) * n1;
        ay += b2f(u0.y) * n0 + b2f(u1.y) * n1;
        az += b2f(u0.z) * n0 + b2f(u1.z) * n1;
        aw += b2f(u0.w) * n0 + b2f(u1.w) * n1;
    }
    if (e < end) {
        int s0 = ebuf[e];
        float n0 = dinv[s0] * di;
        ushort4 u0 = ((const ushort4*)(bases + (size_t)s0 * BFH))[lane];
        ax += b2f(u0.x) * n0; ay += b2f(u0.y) * n0;
        az += b2f(u0.z) * n0; aw += b2f(u0.w) * n0;
    }
    float4 r; r.x = ax; r.y = ay; r.z = az; r.w = aw;
    ((float4*)(agg + (size_t)n * BFH))[lane] = r;
}

// ---------------------------------------------------------------------------
// combine + residual + LayerNorm + ReLU; out holds residual part already.
__global__ __launch_bounds__(512) void combine_kernel(
        const float* __restrict__ agg, const float* __restrict__ weight,
        const float* __restrict__ conv_bias, const float* __restrict__ gamma,
        const float* __restrict__ beta, float* __restrict__ out) {
    int n = blockIdx.x;
    int t = threadIdx.x;
    __shared__ float w[HB];
    __shared__ float rs[8], rs2[8];
    __shared__ float mv[2];
    if (t < HB) w[t] = weight[(size_t)n * HB + t];
    __syncthreads();

    int h = t >> 6, f = t & 63;
    float conv = 0.0f;
    #pragma unroll
    for (int b = 0; b < NB; b++)
        conv += w[h * NB + b] * agg[(size_t)n * BFH + b * FH + f];
    float val = conv + conv_bias[t] + out[(size_t)n * ODIM + t];

    float s = val, s2 = val * val;
    #pragma unroll
    for (int o = 32; o > 0; o >>= 1) {
        s  += __shfl_down(s, o, 64);
        s2 += __shfl_down(s2, o, 64);
    }
    int wid = t >> 6, lane = t & 63;
    if (lane == 0) { rs[wid] = s; rs2[wid] = s2; }
    __syncthreads();
    if (t == 0) {
        float S = 0.f, S2 = 0.f;
        #pragma unroll
        for (int i = 0; i < 8; i++) { S += rs[i]; S2 += rs2[i]; }
        float mu = S / (float)ODIM;
        float var = S2 / (float)ODIM - mu * mu;
        mv[0] = mu;
        mv[1] = rsqrtf(var + LN_EPS);
    }
    __syncthreads();
    float o = (val - mv[0]) * mv[1] * gamma[t] + beta[t];
    out[(size_t)n * ODIM + t] = fmaxf(o, 0.0f);
}

// ---------------------------------------------------------------------------
static inline char* ws_alloc(char*& p, size_t bytes) {
    char* r = p;
    p += (bytes + 255) & ~(size_t)255;
    return r;
}

extern "C" void kernel_launch(void* const* d_in, const int* in_sizes, int n_in,
                              void* d_out, int out_size, void* d_ws, size_t ws_size,
                              hipStream_t stream) {
    const float* x         = (const float*)d_in[0];
    const int*   ei        = (const int*)d_in[1];
    const float* W_bases   = (const float*)d_in[2];
    const float* W_comb    = (const float*)d_in[3];
    const float* b_comb    = (const float*)d_in[4];
    const float* conv_bias = (const float*)d_in[5];
    const float* W_res     = (const float*)d_in[6];
    const float* b_res     = (const float*)d_in[7];
    const float* gamma     = (const float*)d_in[8];
    const float* beta      = (const float*)d_in[9];

    int N = in_sizes[0] / KDIM;
    int E = in_sizes[1] / 2;
    const int* src = ei;
    const int* dst = ei + E;

    char* p = (char*)d_ws;
    int*   deg      = (int*)ws_alloc(p, sizeof(int) * (size_t)N);
    int*   offsets  = (int*)ws_alloc(p, sizeof(int) * (size_t)(N + 1));
    int*   woff     = (int*)ws_alloc(p, sizeof(int) * (size_t)N);
    int*   ebuf     = (int*)ws_alloc(p, sizeof(int) * (size_t)E);
    float* dinv     = (float*)ws_alloc(p, sizeof(float) * (size_t)N);
    float* agg      = (float*)ws_alloc(p, sizeof(float) * (size_t)N * BFH);
    float* weight   = (float*)ws_alloc(p, sizeof(float) * (size_t)N * HB);
    float* bias_cat = (float*)ws_alloc(p, sizeof(float) * NCAT);
    unsigned short* bases = (unsigned short*)ws_alloc(p, 2ull * N * BFH);
    unsigned short* xb    = (unsigned short*)ws_alloc(p, 2ull * N * KDIM);
    unsigned short* wT    = (unsigned short*)ws_alloc(p, 2ull * NCAT * KDIM);
    float* out = (float*)d_out;

    hipMemsetAsync(deg, 0, sizeof(int) * (size_t)N, stream);

    // conversions (independent of graph pipeline)
    long total4 = (long)N * KDIM / 4;
    cvt_x_kernel<<<(total4 + 255) / 256, 256, 0, stream>>>(x, xb, total4);
    stage_w_kernel<<<(NCAT * KDIM + 255) / 256, 256, 0, stream>>>(
        W_bases, W_comb, W_res, b_comb, b_res, wT, bias_cat);

    // graph prep
    deg_kernel<<<(E + 255) / 256, 256, 0, stream>>>(dst, deg, E);
    dinv_kernel<<<(N + 255) / 256, 256, 0, stream>>>(deg, dinv, N);
    scan_kernel<<<1, SCAN_T, 0, stream>>>(deg, offsets, woff, N);
    fill_kernel<<<(E + 255) / 256, 256, 0, stream>>>(src, dst, woff, ebuf, E);

    // fused MFMA GEMM
    dim3 gg(NCAT / BN, (N + BM - 1) / BM);
    mfma_gemm_kernel<<<gg, 256, 0, stream>>>(xb, wT, bias_cat, bases, weight, out, N);

    // aggregate + combine
    gather_kernel<<<(N + 3) / 4, 256, 0, stream>>>(offsets, ebuf, dinv, bases, agg, N);
    combine_kernel<<<N, 512, 0, stream>>>(agg, weight, conv_bias, gamma, beta, out);
}